// Round 11
// baseline (234.509 us; speedup 1.0000x reference)
//
#include <hip/hip_runtime.h>

typedef __attribute__((ext_vector_type(8))) short bf16x8;
typedef __attribute__((ext_vector_type(4))) float f32x4;

constexpr float LN_EPS = 1e-5f;

__device__ inline ushort f2bf(float f) {
  uint u = __float_as_uint(f);
  u += 0x7FFF + ((u >> 16) & 1);   // round-to-nearest-even
  return (ushort)(u >> 16);
}
__device__ inline float bflo(uint u) { return __uint_as_float(u << 16); }
__device__ inline float bfhi(uint u) { return __uint_as_float(u & 0xFFFF0000u); }
__device__ inline uint pk2(float lo, float hi) { return (uint)f2bf(lo) | ((uint)f2bf(hi) << 16); }

struct Params {
  const float* x; const int* ei;
  const float *W_ne, *b_ne, *W_l, *b_l, *W_r, *gamma, *beta, *W_lin, *b_lin;
  float* out;
  ushort *Qbf, *H1, *Dbf, *WAt, *WBt, *Wlt, *Wrt, *Wlint;
  signed char* Aq;          // gathered operand, int8 [N][128]
  float* Ascale;            // per-row scale [N]
  float *bA, *bB;
  int *cnt, *incl, *rowptr, *cursor, *bsums, *srclist;
  int N, E, nbS, nbT, nbT2;
};

// ================= CSR + prep =================

__global__ __launch_bounds__(256) void k_hist(Params p) {
  int e = blockIdx.x * 256 + threadIdx.x;
  if (e < p.E) atomicAdd(&p.cnt[p.ei[p.E + e]], 1);
}

// scan1 (nbS blocks) | WA/WB/bias prep (129 blocks) | weight transpose-casts (rest)
__global__ __launch_bounds__(256) void k_p2(Params p) {
  __shared__ int sh[256];
  const int tid = threadIdx.x, bid = blockIdx.x;
  if (bid < p.nbS) {
    int i = bid * 256 + tid;
    int v = (i < p.N) ? p.cnt[i] : 0;
    sh[tid] = v;
    __syncthreads();
    for (int off = 1; off < 256; off <<= 1) {
      int t = (tid >= off) ? sh[tid - off] : 0;
      __syncthreads();
      sh[tid] += t;
      __syncthreads();
    }
    if (i < p.N) p.incl[i] = sh[tid];
    if (tid == 255) p.bsums[bid] = sh[255];
  } else if (bid < p.nbS + 129) {
    int blk = bid - p.nbS;
    float* srow = (float*)sh;
    const float* src = (blk < 128) ? (p.W_ne + blk * 128) : p.b_ne;
    if (tid < 128) srow[tid] = src[tid];
    __syncthreads();
    int col = tid & 127;
    const float* Wx = (tid < 128) ? p.W_l : p.W_r;
    float acc = 0.f;
#pragma unroll 8
    for (int k = 0; k < 128; ++k) acc = fmaf(srow[k], Wx[k * 128 + col], acc);
    if (blk < 128) {
      ushort* dst = (tid < 128) ? p.WAt : p.WBt;
      dst[col * 128 + blk] = f2bf(acc);
    } else {
      float* dst = (tid < 128) ? p.bA : p.bB;
      dst[col] = acc;
    }
  } else {
    const int total = 16384 + 16384 + 8192;
    const int i0 = (bid - (p.nbS + 129)) * 256 + tid;
    const int st = (gridDim.x - (p.nbS + 129)) * 256;
    for (int idx = i0; idx < total; idx += st) {
      int t = idx;
      if (t < 16384) { p.Wlt[(t & 127) * 128 + (t >> 7)] = f2bf(p.W_l[t]); continue; }
      t -= 16384;
      if (t < 16384) { p.Wrt[(t & 127) * 128 + (t >> 7)] = f2bf(p.W_r[t]); continue; }
      t -= 16384;
      p.Wlint[(t & 63) * 128 + (t >> 6)] = f2bf(p.W_lin[t]);
    }
  }
}

__global__ __launch_bounds__(256) void k_fill(Params p) {
  int e = blockIdx.x * 256 + threadIdx.x;
  if (e >= p.E) return;
  int s = p.ei[e], d = p.ei[p.E + e];
  int pos = atomicAdd(&p.cursor[d], 1);
  p.srclist[pos] = s;
}

// ================= A-shared pair GEMM =================
// Tile: 64 rows x [W1(128) | W2(128)]. 4 waves: (wave>>1)=row half (32 rows), (wave&1)=weight.
// Weight-half 0 -> int8 quant + per-row scale (Yq, Yscale); weight-half 1 -> bf16 (Ybf).
// F32A: A is fp32, converted in-register (same rounding as pre-cast path).

template <bool F32A>
__device__ __forceinline__ void gemm_pair_tile(const void* __restrict__ Xv,
                                               const ushort* __restrict__ Wt1, const ushort* __restrict__ Wt2,
                                               const float* __restrict__ bias1, const float* __restrict__ bias2,
                                               signed char* __restrict__ Yq, float* __restrict__ Yscale,
                                               ushort* __restrict__ Ybf, int M, int tile,
                                               signed char (*qt)[128]) {
  const int tid = threadIdx.x;
  const int wave = tid >> 6, lane = tid & 63;
  const int rbase = (wave >> 1) * 32;
  const int chalf = wave & 1;
  const ushort* Wt = chalf ? Wt2 : Wt1;
  const float* bias = chalf ? bias2 : bias1;
  const int lrow = lane & 15;
  const int lkb = (lane >> 4) * 8;
  const int row0 = tile * 64;

  size_t rIdx[2];
#pragma unroll
  for (int mf = 0; mf < 2; ++mf) {
    int r = row0 + rbase + mf * 16 + lrow;
    rIdx[mf] = (size_t)((r < M) ? r : (M - 1));
  }

  f32x4 acc[2][8];
#pragma unroll
  for (int mf = 0; mf < 2; ++mf)
#pragma unroll
    for (int nf = 0; nf < 8; ++nf) acc[mf][nf] = (f32x4){0.f, 0.f, 0.f, 0.f};

#pragma unroll
  for (int ks = 0; ks < 4; ++ks) {
    bf16x8 a[2], b[8];
#pragma unroll
    for (int mf = 0; mf < 2; ++mf) {
      if constexpr (F32A) {
        const float* Xf = (const float*)Xv + rIdx[mf] * 128 + ks * 32 + lkb;
        float4 lo = *(const float4*)Xf;
        float4 hi = *(const float4*)(Xf + 4);
        uint4 v;
        v.x = pk2(lo.x, lo.y); v.y = pk2(lo.z, lo.w);
        v.z = pk2(hi.x, hi.y); v.w = pk2(hi.z, hi.w);
        a[mf] = *reinterpret_cast<bf16x8*>(&v);
      } else {
        a[mf] = *(const bf16x8*)((const ushort*)Xv + rIdx[mf] * 128 + ks * 32 + lkb);
      }
    }
#pragma unroll
    for (int nf = 0; nf < 8; ++nf)
      b[nf] = *(const bf16x8*)(Wt + (size_t)(nf * 16 + lrow) * 128 + ks * 32 + lkb);
#pragma unroll
    for (int mf = 0; mf < 2; ++mf)
#pragma unroll
      for (int nf = 0; nf < 8; ++nf)
        acc[mf][nf] = __builtin_amdgcn_mfma_f32_16x16x32_bf16(a[mf], b[nf], acc[mf][nf], 0, 0, 0);
  }

  if (bias) {
#pragma unroll
    for (int nf = 0; nf < 8; ++nf) {
      float bv = bias[nf * 16 + lrow];
#pragma unroll
      for (int mf = 0; mf < 2; ++mf)
#pragma unroll
        for (int r = 0; r < 4; ++r) acc[mf][nf][r] += bv;
    }
  }

  if (chalf == 0) {
    // int8 quant: wave owns full 128-col rows -> in-wave row-max
#pragma unroll
    for (int mf = 0; mf < 2; ++mf)
#pragma unroll
      for (int r = 0; r < 4; ++r) {
        float m = 0.f;
#pragma unroll
        for (int nf = 0; nf < 8; ++nf) m = fmaxf(m, fabsf(acc[mf][nf][r]));
#pragma unroll
        for (int off = 1; off < 16; off <<= 1) m = fmaxf(m, __shfl_xor(m, off, 64));
        int lr = rbase + mf * 16 + (lane >> 4) * 4 + r;
        float inv = (m > 0.f) ? 127.f / m : 0.f;
#pragma unroll
        for (int nf = 0; nf < 8; ++nf)
          qt[lr][nf * 16 + lrow] = (signed char)__float2int_rn(acc[mf][nf][r] * inv);
        int grow = row0 + lr;
        if (lrow == 0 && grow < M) Yscale[grow] = m * (1.f / 127.f);
      }
  } else {
    // bf16 out
#pragma unroll
    for (int nf = 0; nf < 8; ++nf) {
      int col = nf * 16 + lrow;
#pragma unroll
      for (int mf = 0; mf < 2; ++mf) {
        int growb = row0 + rbase + mf * 16 + (lane >> 4) * 4;
#pragma unroll
        for (int r = 0; r < 4; ++r) {
          int grow = growb + r;
          if (grow < M) Ybf[(size_t)grow * 128 + col] = f2bf(acc[mf][nf][r]);
        }
      }
    }
  }
  __syncthreads();
  // copy quant tile out (coalesced)
  for (int idx = tid; idx < 512; idx += 256) {
    int lr = idx >> 3, co = (idx & 7) * 16;
    int grow = row0 + lr;
    if (grow < M) *(uint4*)(Yq + (size_t)grow * 128 + co) = *(const uint4*)&qt[lr][co];
  }
}

// rowptr/cursor with folded bsums-prefix (nbS blocks) | GEMM1 pair from fp32 x
__global__ __launch_bounds__(256) void k_p4(Params p) {
  __shared__ __align__(16) signed char qt[64][128];
  const int bid = blockIdx.x, tid = threadIdx.x;
  if (bid < p.nbS) {
    int* ss = (int*)qt;
    int v = (tid < bid) ? p.bsums[tid] : 0;
    ss[tid] = v;
    __syncthreads();
    for (int off = 128; off > 0; off >>= 1) {
      if (tid < off) ss[tid] += ss[tid + off];
      __syncthreads();
    }
    int prefix = ss[0];
    int i = bid * 256 + tid;
    if (i < p.N) {
      int inc = p.incl[i] + prefix;
      p.rowptr[i + 1] = inc;
      p.cursor[i] = inc - p.cnt[i];
    }
    if (i == 0) p.rowptr[0] = 0;
    return;
  }
  gemm_pair_tile<true>(p.x, p.WAt, p.WBt, p.bA, p.bB, p.Aq, p.Ascale, p.Qbf, p.N, bid - p.nbS, qt);
}

__global__ __launch_bounds__(256) void k_gemm2(Params p) {
  __shared__ __align__(16) signed char qt[64][128];
  gemm_pair_tile<false>(p.Dbf, p.Wlt, p.Wrt, nullptr, nullptr, p.Aq, p.Ascale, p.Qbf, p.N, blockIdx.x, qt);
}

// ================= out GEMM: 128 rows x 64 cols, 4 waves 2x2, f32 out =================

__global__ __launch_bounds__(256) void k_gout(Params p) {
  const int tid = threadIdx.x;
  const int wave = tid >> 6, lane = tid & 63;
  const int rbase = (wave >> 1) * 64;
  const int cbase = (wave & 1) * 32;
  const int lrow = lane & 15;
  const int lkb = (lane >> 4) * 8;
  const int row0 = blockIdx.x * 128;
  const ushort* X = p.Dbf;

  size_t rIdx[4];
#pragma unroll
  for (int mf = 0; mf < 4; ++mf) {
    int r = row0 + rbase + mf * 16 + lrow;
    rIdx[mf] = (size_t)((r < p.N) ? r : (p.N - 1));
  }
  f32x4 acc[4][2];
#pragma unroll
  for (int mf = 0; mf < 4; ++mf)
#pragma unroll
    for (int nf = 0; nf < 2; ++nf) acc[mf][nf] = (f32x4){0.f, 0.f, 0.f, 0.f};
#pragma unroll
  for (int ks = 0; ks < 4; ++ks) {
    bf16x8 a[4], b[2];
#pragma unroll
    for (int mf = 0; mf < 4; ++mf)
      a[mf] = *(const bf16x8*)(X + rIdx[mf] * 128 + ks * 32 + lkb);
#pragma unroll
    for (int nf = 0; nf < 2; ++nf)
      b[nf] = *(const bf16x8*)(p.Wlint + (size_t)(cbase + nf * 16 + lrow) * 128 + ks * 32 + lkb);
#pragma unroll
    for (int mf = 0; mf < 4; ++mf)
#pragma unroll
      for (int nf = 0; nf < 2; ++nf)
        acc[mf][nf] = __builtin_amdgcn_mfma_f32_16x16x32_bf16(a[mf], b[nf], acc[mf][nf], 0, 0, 0);
  }
#pragma unroll
  for (int nf = 0; nf < 2; ++nf) {
    int col = cbase + nf * 16 + lrow;
    float bv = p.b_lin[col];
#pragma unroll
    for (int mf = 0; mf < 4; ++mf) {
      int growb = row0 + rbase + mf * 16 + (lane >> 4) * 4;
#pragma unroll
      for (int r = 0; r < 4; ++r) {
        int grow = growb + r;
        if (grow < p.N) p.out[(size_t)grow * 64 + col] = acc[mf][nf][r] + bv;
      }
    }
  }
}

// ================= gather/LN: wave per node, 16 edges/iter, int8 rows + per-row scale =================

__device__ __forceinline__ void acc8q(uint2 u, float sc, float* a) {
  a[0] = fmaf((float)(int)(signed char)(u.x & 0xFF), sc, a[0]);
  a[1] = fmaf((float)(int)(signed char)((u.x >> 8) & 0xFF), sc, a[1]);
  a[2] = fmaf((float)(int)(signed char)((u.x >> 16) & 0xFF), sc, a[2]);
  a[3] = fmaf((float)(int)(signed char)(u.x >> 24), sc, a[3]);
  a[4] = fmaf((float)(int)(signed char)(u.y & 0xFF), sc, a[4]);
  a[5] = fmaf((float)(int)(signed char)((u.y >> 8) & 0xFF), sc, a[5]);
  a[6] = fmaf((float)(int)(signed char)((u.y >> 16) & 0xFF), sc, a[6]);
  a[7] = fmaf((float)(int)(signed char)(u.y >> 24), sc, a[7]);
}

__device__ __forceinline__ void gather_mean(const signed char* __restrict__ Pq, const float* __restrict__ Psc,
                                            const int* __restrict__ rowptr, const int* __restrict__ srclist,
                                            int w, int lane, float* a) {
  int fl = lane & 15, g4 = lane >> 4;
  int beg = rowptr[w], end = rowptr[w + 1];
  for (int base = beg; base < end; base += 64) {
    int m = end - base;
    if (m > 64) m = 64;
    int sidx = (lane < m) ? srclist[base + lane] : 0;
    for (int i = 0; i < m; i += 16) {
      int j0 = i + g4, j1 = j0 + 4, j2 = j0 + 8, j3 = j0 + 12;
      int s0 = __shfl(sidx, j0 & 63, 64);
      int s1 = __shfl(sidx, j1 & 63, 64);
      int s2 = __shfl(sidx, j2 & 63, 64);
      int s3 = __shfl(sidx, j3 & 63, 64);
      float c0 = Psc[s0], c1 = Psc[s1], c2 = Psc[s2], c3 = Psc[s3];
      uint2 u0 = *(const uint2*)(Pq + (size_t)s0 * 128 + fl * 8);   // unconditional: indices valid
      uint2 u1 = *(const uint2*)(Pq + (size_t)s1 * 128 + fl * 8);
      uint2 u2 = *(const uint2*)(Pq + (size_t)s2 * 128 + fl * 8);
      uint2 u3 = *(const uint2*)(Pq + (size_t)s3 * 128 + fl * 8);
      if (j0 < m) acc8q(u0, c0, a);
      if (j1 < m) acc8q(u1, c1, a);
      if (j2 < m) acc8q(u2, c2, a);
      if (j3 < m) acc8q(u3, c3, a);
    }
  }
#pragma unroll
  for (int k = 0; k < 8; ++k) {
    a[k] += __shfl_xor(a[k], 16, 64);
    a[k] += __shfl_xor(a[k], 32, 64);
  }
  float inv = 1.f / fmaxf((float)(end - beg), 1.f);
#pragma unroll
  for (int k = 0; k < 8; ++k) a[k] *= inv;
}

__device__ __forceinline__ void ln_relu8(const float* h, const float* __restrict__ gamma,
                                         const float* __restrict__ beta, int fl, float* o) {
  float sum = 0.f;
#pragma unroll
  for (int k = 0; k < 8; ++k) sum += h[k];
#pragma unroll
  for (int off = 1; off < 16; off <<= 1) sum += __shfl_xor(sum, off, 64);
  float mu = sum * (1.f / 128.f);
  float s2 = 0.f;
#pragma unroll
  for (int k = 0; k < 8; ++k) { float d = h[k] - mu; s2 += d * d; }
#pragma unroll
  for (int off = 1; off < 16; off <<= 1) s2 += __shfl_xor(s2, off, 64);
  float scale = rsqrtf(s2 * (1.f / 128.f) + LN_EPS);
  float4 g0 = *(const float4*)(gamma + fl * 8);
  float4 g1 = *(const float4*)(gamma + fl * 8 + 4);
  float4 b0 = *(const float4*)(beta + fl * 8);
  float4 b1 = *(const float4*)(beta + fl * 8 + 4);
  float gg[8] = {g0.x, g0.y, g0.z, g0.w, g1.x, g1.y, g1.z, g1.w};
  float bb[8] = {b0.x, b0.y, b0.z, b0.w, b1.x, b1.y, b1.z, b1.w};
#pragma unroll
  for (int k = 0; k < 8; ++k) o[k] = fmaxf((h[k] - mu) * scale * gg[k] + bb[k], 0.f);
}

__device__ __forceinline__ uint4 pack8(const float* v) {
  uint4 u;
  u.x = pk2(v[0], v[1]); u.y = pk2(v[2], v[3]);
  u.z = pk2(v[4], v[5]); u.w = pk2(v[6], v[7]);
  return u;
}

// agg1: h1 = mean(Aq)+Qbf+b_l -> H1 (bf16); r = relu(LN(h1)) -> Dbf (bf16)
__global__ __launch_bounds__(256) void k_agg1(Params p) {
  int w = (blockIdx.x * 256 + threadIdx.x) >> 6;
  int lane = threadIdx.x & 63;
  if (w >= p.N) return;
  int fl = lane & 15;
  float a[8] = {0.f, 0.f, 0.f, 0.f, 0.f, 0.f, 0.f, 0.f};
  gather_mean(p.Aq, p.Ascale, p.rowptr, p.srclist, w, lane, a);
  uint4 qv = ((const uint4*)p.Qbf)[(size_t)w * 16 + fl];
  float4 bl0 = *(const float4*)(p.b_l + fl * 8);
  float4 bl1 = *(const float4*)(p.b_l + fl * 8 + 4);
  float q[8] = {bflo(qv.x), bfhi(qv.x), bflo(qv.y), bfhi(qv.y), bflo(qv.z), bfhi(qv.z), bflo(qv.w), bfhi(qv.w)};
  float bl[8] = {bl0.x, bl0.y, bl0.z, bl0.w, bl1.x, bl1.y, bl1.z, bl1.w};
  float h[8];
#pragma unroll
  for (int k = 0; k < 8; ++k) h[k] = a[k] + q[k] + bl[k];
  float r[8];
  ln_relu8(h, p.gamma, p.beta, fl, r);
  if (lane < 16) {
    ((uint4*)p.H1)[(size_t)w * 16 + fl] = pack8(h);
    ((uint4*)p.Dbf)[(size_t)w * 16 + fl] = pack8(r);
  }
}

// agg2: o = relu(LN(mean(Aq)+Qbf+b_l+h1)) -> Dbf (bf16)
__global__ __launch_bounds__(256) void k_agg2(Params p) {
  int w = (blockIdx.x * 256 + threadIdx.x) >> 6;
  int lane = threadIdx.x & 63;
  if (w >= p.N) return;
  int fl = lane & 15;
  float a[8] = {0.f, 0.f, 0.f, 0.f, 0.f, 0.f, 0.f, 0.f};
  gather_mean(p.Aq, p.Ascale, p.rowptr, p.srclist, w, lane, a);
  uint4 vv = ((const uint4*)p.Qbf)[(size_t)w * 16 + fl];
  uint4 hv = ((const uint4*)p.H1)[(size_t)w * 16 + fl];
  float4 bl0 = *(const float4*)(p.b_l + fl * 8);
  float4 bl1 = *(const float4*)(p.b_l + fl * 8 + 4);
  float vf[8] = {bflo(vv.x), bfhi(vv.x), bflo(vv.y), bfhi(vv.y), bflo(vv.z), bfhi(vv.z), bflo(vv.w), bfhi(vv.w)};
  float hf[8] = {bflo(hv.x), bfhi(hv.x), bflo(hv.y), bfhi(hv.y), bflo(hv.z), bfhi(hv.z), bflo(hv.w), bfhi(hv.w)};
  float bl[8] = {bl0.x, bl0.y, bl0.z, bl0.w, bl1.x, bl1.y, bl1.z, bl1.w};
  float h[8];
#pragma unroll
  for (int k = 0; k < 8; ++k) h[k] = a[k] + vf[k] + bl[k] + hf[k];
  float o[8];
  ln_relu8(h, p.gamma, p.beta, fl, o);
  if (lane < 16) ((uint4*)p.Dbf)[(size_t)w * 16 + fl] = pack8(o);
}

// ================= launch =================

extern "C" void kernel_launch(void* const* d_in, const int* in_sizes, int n_in,
                              void* d_out, int out_size, void* d_ws, size_t ws_size,
                              hipStream_t stream) {
  Params p;
  p.x = (const float*)d_in[0];
  p.ei = (const int*)d_in[1];
  // d_in[2] = edge_attr: unused by the reference
  p.W_ne = (const float*)d_in[3];
  p.b_ne = (const float*)d_in[4];
  p.W_l = (const float*)d_in[5];
  p.b_l = (const float*)d_in[6];
  p.W_r = (const float*)d_in[7];
  p.gamma = (const float*)d_in[8];
  p.beta = (const float*)d_in[9];
  p.W_lin = (const float*)d_in[10];
  p.b_lin = (const float*)d_in[11];
  p.out = (float*)d_out;

  p.N = in_sizes[0] / 128;
  p.E = in_sizes[1] / 2;
  p.nbS = (p.N + 255) / 256;
  p.nbT = (p.N + 127) / 128;
  p.nbT2 = (p.N + 63) / 64;

  char* w = (char*)d_ws;
  const size_t S2 = (size_t)p.N * 128 * sizeof(ushort);
  p.Qbf = (ushort*)w;    w += S2;
  p.H1 = (ushort*)w;     w += S2;
  p.Dbf = (ushort*)w;    w += S2;
  p.Aq = (signed char*)w;  w += (size_t)p.N * 128;
  p.Ascale = (float*)w;  w += (size_t)p.N * sizeof(float);
  p.WAt = (ushort*)w;    w += 128 * 128 * sizeof(ushort);
  p.WBt = (ushort*)w;    w += 128 * 128 * sizeof(ushort);
  p.Wlt = (ushort*)w;    w += 128 * 128 * sizeof(ushort);
  p.Wrt = (ushort*)w;    w += 128 * 128 * sizeof(ushort);
  p.Wlint = (ushort*)w;  w += 64 * 128 * sizeof(ushort);
  p.bA = (float*)w;      w += 128 * sizeof(float);
  p.bB = (float*)w;      w += 128 * sizeof(float);
  p.cnt = (int*)w;       w += (size_t)p.N * sizeof(int);
  p.incl = (int*)w;      w += (size_t)p.N * sizeof(int);
  p.rowptr = (int*)w;    w += ((size_t)p.N + 4) * sizeof(int);
  p.cursor = (int*)w;    w += (size_t)p.N * sizeof(int);
  p.bsums = (int*)w;     w += 1024 * sizeof(int);
  p.srclist = (int*)w;

  const int nbE = (p.E + 255) / 256;
  const int nbW = ((p.N * 64) + 255) / 256;

  hipMemsetAsync(p.cnt, 0, (size_t)p.N * sizeof(int), stream);
  k_hist<<<nbE, 256, 0, stream>>>(p);
  k_p2<<<p.nbS + 129 + 64, 256, 0, stream>>>(p);
  k_p4<<<p.nbS + p.nbT2, 256, 0, stream>>>(p);
  k_fill<<<nbE, 256, 0, stream>>>(p);
  k_agg1<<<nbW, 256, 0, stream>>>(p);
  k_gemm2<<<p.nbT2, 256, 0, stream>>>(p);
  k_agg2<<<nbW, 256, 0, stream>>>(p);
  k_gout<<<p.nbT, 256, 0, stream>>>(p);
}

// Round 13
// 218.529 us; speedup vs baseline: 1.0731x; 1.0731x over previous
//
#include <hip/hip_runtime.h>

typedef __attribute__((ext_vector_type(8))) short bf16x8;
typedef __attribute__((ext_vector_type(4))) float f32x4;

constexpr float LN_EPS = 1e-5f;

__device__ inline ushort f2bf(float f) {
  uint u = __float_as_uint(f);
  u += 0x7FFF + ((u >> 16) & 1);   // round-to-nearest-even
  return (ushort)(u >> 16);
}
__device__ inline float bflo(uint u) { return __uint_as_float(u << 16); }
__device__ inline float bfhi(uint u) { return __uint_as_float(u & 0xFFFF0000u); }
__device__ inline uint pk2(float lo, float hi) { return (uint)f2bf(lo) | ((uint)f2bf(hi) << 16); }

struct Params {
  const float* x; const int* ei;
  const float *W_ne, *b_ne, *W_l, *b_l, *W_r, *gamma, *beta, *W_lin, *b_lin;
  float* out;
  ushort *Qbf, *H1, *Dbf, *xbf, *WAt, *WBt, *Wlt, *Wrt, *Wlint;
  signed char* Aq;          // gathered operand, int8 [N][128]
  float* Ascale;            // per-row scale [N]
  float *bA, *bB;
  int *cnt, *incl, *rowptr, *cursor, *bsums, *srclist;
  int N, E, nbS, nbT, nbE;
};

// ================= m1: hist | WA/WB/bias prep | x-cast + weight casts =================

__global__ __launch_bounds__(256) void k_m1(Params p) {
  __shared__ float srow[128];
  const int tid = threadIdx.x, bid = blockIdx.x;
  if (bid < p.nbE) {
    int e = bid * 256 + tid;
    if (e < p.E) atomicAdd(&p.cnt[p.ei[p.E + e]], 1);
  } else if (bid < p.nbE + 129) {
    int blk = bid - p.nbE;
    const float* src = (blk < 128) ? (p.W_ne + blk * 128) : p.b_ne;
    if (tid < 128) srow[tid] = src[tid];
    __syncthreads();
    int col = tid & 127;
    const float* Wx = (tid < 128) ? p.W_l : p.W_r;
    float acc = 0.f;
#pragma unroll 8
    for (int k = 0; k < 128; ++k) acc = fmaf(srow[k], Wx[k * 128 + col], acc);
    if (blk < 128) {
      ushort* dst = (tid < 128) ? p.WAt : p.WBt;
      dst[col * 128 + blk] = f2bf(acc);
    } else {
      float* dst = (tid < 128) ? p.bA : p.bB;
      dst[col] = acc;
    }
  } else {
    const int nx16 = p.N * 16;
    const int total = nx16 + 16384 + 16384 + 8192;
    const int i0 = (bid - (p.nbE + 129)) * 256 + tid;
    const int st = (gridDim.x - (p.nbE + 129)) * 256;
    const float4* xin = (const float4*)p.x;
    uint4* xo = (uint4*)p.xbf;
    for (int idx = i0; idx < total; idx += st) {
      if (idx < nx16) {
        float4 a = xin[2 * (size_t)idx], b = xin[2 * (size_t)idx + 1];
        uint4 v;
        v.x = pk2(a.x, a.y); v.y = pk2(a.z, a.w);
        v.z = pk2(b.x, b.y); v.w = pk2(b.z, b.w);
        xo[idx] = v;
        continue;
      }
      int t = idx - nx16;
      if (t < 16384) { p.Wlt[(t & 127) * 128 + (t >> 7)] = f2bf(p.W_l[t]); continue; }
      t -= 16384;
      if (t < 16384) { p.Wrt[(t & 127) * 128 + (t >> 7)] = f2bf(p.W_r[t]); continue; }
      t -= 16384;
      p.Wlint[(t & 63) * 128 + (t >> 6)] = f2bf(p.W_lin[t]);
    }
  }
}

// ================= no-LDS MFMA GEMM: 128 rows x NCOL, 4 waves 2x2 =================
// X bf16 [M][128]; Wt bf16 [NCOL][128]. OMODE: 0=f32, 1=bf16, 2=int8+per-row-scale.

template <int NCOL, int OMODE>
__device__ __forceinline__ void gemm_tile(const ushort* __restrict__ X, const ushort* __restrict__ Wt,
                                          const float* __restrict__ bias, void* __restrict__ Yv,
                                          float* __restrict__ Yscale, int M, int tile, char* ldsraw) {
  constexpr int NF = NCOL / 32;
  const int tid = threadIdx.x;
  const int wave = tid >> 6, lane = tid & 63;
  const int rbase = (wave >> 1) * 64;
  const int cbase = (wave & 1) * (NCOL / 2);
  const int lrow = lane & 15;
  const int lkb = (lane >> 4) * 8;
  const int row0 = tile * 128;

  size_t rIdx[4];
#pragma unroll
  for (int mf = 0; mf < 4; ++mf) {
    int r = row0 + rbase + mf * 16 + lrow;
    rIdx[mf] = (size_t)((r < M) ? r : (M - 1));
  }

  f32x4 acc[4][NF];
#pragma unroll
  for (int mf = 0; mf < 4; ++mf)
#pragma unroll
    for (int nf = 0; nf < NF; ++nf) acc[mf][nf] = (f32x4){0.f, 0.f, 0.f, 0.f};

#pragma unroll
  for (int ks = 0; ks < 4; ++ks) {
    bf16x8 a[4], b[NF];
#pragma unroll
    for (int mf = 0; mf < 4; ++mf)
      a[mf] = *(const bf16x8*)(X + rIdx[mf] * 128 + ks * 32 + lkb);
#pragma unroll
    for (int nf = 0; nf < NF; ++nf)
      b[nf] = *(const bf16x8*)(Wt + (size_t)(cbase + nf * 16 + lrow) * 128 + ks * 32 + lkb);
#pragma unroll
    for (int mf = 0; mf < 4; ++mf)
#pragma unroll
      for (int nf = 0; nf < NF; ++nf)
        acc[mf][nf] = __builtin_amdgcn_mfma_f32_16x16x32_bf16(a[mf], b[nf], acc[mf][nf], 0, 0, 0);
  }

  if (bias) {
#pragma unroll
    for (int nf = 0; nf < NF; ++nf) {
      float bv = bias[cbase + nf * 16 + lrow];
#pragma unroll
      for (int mf = 0; mf < 4; ++mf)
#pragma unroll
        for (int r = 0; r < 4; ++r) acc[mf][nf][r] += bv;
    }
  }

  if constexpr (OMODE == 2) {
    float (*rmaxh)[2] = (float(*)[2])ldsraw;            // [128][2]
    signed char (*qt)[128] = (signed char(*)[128])(ldsraw + 1024);  // [128][128]
#pragma unroll
    for (int mf = 0; mf < 4; ++mf)
#pragma unroll
      for (int r = 0; r < 4; ++r) {
        float m = 0.f;
#pragma unroll
        for (int nf = 0; nf < NF; ++nf) m = fmaxf(m, fabsf(acc[mf][nf][r]));
#pragma unroll
        for (int off = 1; off < 16; off <<= 1) m = fmaxf(m, __shfl_xor(m, off, 64));
        int lr = rbase + mf * 16 + (lane >> 4) * 4 + r;
        if (lrow == 0) rmaxh[lr][wave & 1] = m;
      }
    __syncthreads();
#pragma unroll
    for (int mf = 0; mf < 4; ++mf)
#pragma unroll
      for (int r = 0; r < 4; ++r) {
        int lr = rbase + mf * 16 + (lane >> 4) * 4 + r;
        float mx = fmaxf(rmaxh[lr][0], rmaxh[lr][1]);
        float inv = (mx > 0.f) ? 127.f / mx : 0.f;
#pragma unroll
        for (int nf = 0; nf < NF; ++nf)
          qt[lr][cbase + nf * 16 + lrow] = (signed char)__float2int_rn(acc[mf][nf][r] * inv);
      }
    __syncthreads();
    signed char* Yq = (signed char*)Yv;
    for (int idx = tid; idx < 1024; idx += 256) {
      int lr = idx >> 3, co = (idx & 7) * 16;
      int grow = row0 + lr;
      if (grow < M) *(uint4*)(Yq + (size_t)grow * 128 + co) = *(const uint4*)&qt[lr][co];
    }
    if (tid < 128) {
      int grow = row0 + tid;
      if (grow < M) Yscale[grow] = fmaxf(rmaxh[tid][0], rmaxh[tid][1]) * (1.f / 127.f);
    }
    return;
  }

#pragma unroll
  for (int nf = 0; nf < NF; ++nf) {
    int col = cbase + nf * 16 + lrow;
#pragma unroll
    for (int mf = 0; mf < 4; ++mf) {
      int growb = row0 + rbase + mf * 16 + (lane >> 4) * 4;
#pragma unroll
      for (int r = 0; r < 4; ++r) {
        int grow = growb + r;
        if (grow < M) {
          float val = acc[mf][nf][r];
          if constexpr (OMODE == 1)
            ((ushort*)Yv)[(size_t)grow * NCOL + col] = f2bf(val);
          else
            ((float*)Yv)[(size_t)grow * NCOL + col] = val;
        }
      }
    }
  }
}

// ================= m2: scan1 | GEMM1 pair =================

__global__ __launch_bounds__(256) void k_m2(Params p) {
  __shared__ __align__(16) char qlds[1024 + 16384];
  const int bid = blockIdx.x, tid = threadIdx.x;
  if (bid < p.nbS) {
    int* sh = (int*)qlds;
    int i = bid * 256 + tid;
    int v = (i < p.N) ? p.cnt[i] : 0;
    sh[tid] = v;
    __syncthreads();
    for (int off = 1; off < 256; off <<= 1) {
      int t = (tid >= off) ? sh[tid - off] : 0;
      __syncthreads();
      sh[tid] += t;
      __syncthreads();
    }
    if (i < p.N) p.incl[i] = sh[tid];
    if (tid == 255) p.bsums[bid] = sh[255];
    return;
  }
  int job = bid - p.nbS;
  if (job < p.nbT) gemm_tile<128, 2>(p.xbf, p.WAt, p.bA, p.Aq, p.Ascale, p.N, job, qlds);
  else gemm_tile<128, 1>(p.xbf, p.WBt, p.bB, p.Qbf, nullptr, p.N, job - p.nbT, qlds);
}

// ================= m3: rowptr/cursor with folded bsums-prefix =================

__global__ __launch_bounds__(256) void k_m3(Params p) {
  __shared__ int ss[256];
  const int bid = blockIdx.x, tid = threadIdx.x;
  int v = (tid < bid) ? p.bsums[tid] : 0;
  ss[tid] = v;
  __syncthreads();
  for (int off = 128; off > 0; off >>= 1) {
    if (tid < off) ss[tid] += ss[tid + off];
    __syncthreads();
  }
  int prefix = ss[0];
  int i = bid * 256 + tid;
  if (i < p.N) {
    int inc = p.incl[i] + prefix;
    p.rowptr[i + 1] = inc;
    p.cursor[i] = inc - p.cnt[i];
  }
  if (i == 0) p.rowptr[0] = 0;
}

__global__ __launch_bounds__(256) void k_fill(Params p) {
  int e = blockIdx.x * 256 + threadIdx.x;
  if (e >= p.E) return;
  int s = p.ei[e], d = p.ei[p.E + e];
  int pos = atomicAdd(&p.cursor[d], 1);
  p.srclist[pos] = s;
}

__global__ __launch_bounds__(256) void k_gemm2(Params p) {
  __shared__ __align__(16) char qlds[1024 + 16384];
  int job = blockIdx.y * p.nbT + blockIdx.x;
  if (job < p.nbT) gemm_tile<128, 2>(p.Dbf, p.Wlt, nullptr, p.Aq, p.Ascale, p.N, job, qlds);
  else gemm_tile<128, 1>(p.Dbf, p.Wrt, nullptr, p.Qbf, nullptr, p.N, job - p.nbT, qlds);
}

__global__ __launch_bounds__(256) void k_gout(Params p) {
  gemm_tile<64, 0>(p.Dbf, p.Wlint, p.b_lin, p.out, nullptr, p.N, blockIdx.x, nullptr);
}

// ================= gather/LN: wave per node, 16 edges/iter, int8 rows + per-row scale =================

__device__ __forceinline__ void acc8q(uint2 u, float sc, float* a) {
  a[0] = fmaf((float)(int)(signed char)(u.x & 0xFF), sc, a[0]);
  a[1] = fmaf((float)(int)(signed char)((u.x >> 8) & 0xFF), sc, a[1]);
  a[2] = fmaf((float)(int)(signed char)((u.x >> 16) & 0xFF), sc, a[2]);
  a[3] = fmaf((float)(int)(signed char)(u.x >> 24), sc, a[3]);
  a[4] = fmaf((float)(int)(signed char)(u.y & 0xFF), sc, a[4]);
  a[5] = fmaf((float)(int)(signed char)((u.y >> 8) & 0xFF), sc, a[5]);
  a[6] = fmaf((float)(int)(signed char)((u.y >> 16) & 0xFF), sc, a[6]);
  a[7] = fmaf((float)(int)(signed char)(u.y >> 24), sc, a[7]);
}

__device__ __forceinline__ void gather_mean(const signed char* __restrict__ Pq, const float* __restrict__ Psc,
                                            const int* __restrict__ rowptr, const int* __restrict__ srclist,
                                            int w, int lane, float* a) {
  int fl = lane & 15, g4 = lane >> 4;
  int beg = rowptr[w], end = rowptr[w + 1];
  for (int base = beg; base < end; base += 64) {
    int m = end - base;
    if (m > 64) m = 64;
    int sidx = (lane < m) ? srclist[base + lane] : 0;
    for (int i = 0; i < m; i += 16) {
      int j0 = i + g4, j1 = j0 + 4, j2 = j0 + 8, j3 = j0 + 12;
      int s0 = __shfl(sidx, j0 & 63, 64);
      int s1 = __shfl(sidx, j1 & 63, 64);
      int s2 = __shfl(sidx, j2 & 63, 64);
      int s3 = __shfl(sidx, j3 & 63, 64);
      float c0 = Psc[s0], c1 = Psc[s1], c2 = Psc[s2], c3 = Psc[s3];
      uint2 u0 = *(const uint2*)(Pq + (size_t)s0 * 128 + fl * 8);   // unconditional: indices valid
      uint2 u1 = *(const uint2*)(Pq + (size_t)s1 * 128 + fl * 8);
      uint2 u2 = *(const uint2*)(Pq + (size_t)s2 * 128 + fl * 8);
      uint2 u3 = *(const uint2*)(Pq + (size_t)s3 * 128 + fl * 8);
      if (j0 < m) acc8q(u0, c0, a);
      if (j1 < m) acc8q(u1, c1, a);
      if (j2 < m) acc8q(u2, c2, a);
      if (j3 < m) acc8q(u3, c3, a);
    }
  }
#pragma unroll
  for (int k = 0; k < 8; ++k) {
    a[k] += __shfl_xor(a[k], 16, 64);
    a[k] += __shfl_xor(a[k], 32, 64);
  }
  float inv = 1.f / fmaxf((float)(end - beg), 1.f);
#pragma unroll
  for (int k = 0; k < 8; ++k) a[k] *= inv;
}

__device__ __forceinline__ void ln_relu8(const float* h, const float* __restrict__ gamma,
                                         const float* __restrict__ beta, int fl, float* o) {
  float sum = 0.f;
#pragma unroll
  for (int k = 0; k < 8; ++k) sum += h[k];
#pragma unroll
  for (int off = 1; off < 16; off <<= 1) sum += __shfl_xor(sum, off, 64);
  float mu = sum * (1.f / 128.f);
  float s2 = 0.f;
#pragma unroll
  for (int k = 0; k < 8; ++k) { float d = h[k] - mu; s2 += d * d; }
#pragma unroll
  for (int off = 1; off < 16; off <<= 1) s2 += __shfl_xor(s2, off, 64);
  float scale = rsqrtf(s2 * (1.f / 128.f) + LN_EPS);
  float4 g0 = *(const float4*)(gamma + fl * 8);
  float4 g1 = *(const float4*)(gamma + fl * 8 + 4);
  float4 b0 = *(const float4*)(beta + fl * 8);
  float4 b1 = *(const float4*)(beta + fl * 8 + 4);
  float gg[8] = {g0.x, g0.y, g0.z, g0.w, g1.x, g1.y, g1.z, g1.w};
  float bb[8] = {b0.x, b0.y, b0.z, b0.w, b1.x, b1.y, b1.z, b1.w};
#pragma unroll
  for (int k = 0; k < 8; ++k) o[k] = fmaxf((h[k] - mu) * scale * gg[k] + bb[k], 0.f);
}

__device__ __forceinline__ uint4 pack8(const float* v) {
  uint4 u;
  u.x = pk2(v[0], v[1]); u.y = pk2(v[2], v[3]);
  u.z = pk2(v[4], v[5]); u.w = pk2(v[6], v[7]);
  return u;
}

// agg1: h1 = mean(Aq)+Qbf+b_l -> H1 (bf16); r = relu(LN(h1)) -> Dbf (bf16)
__global__ __launch_bounds__(256) void k_agg1(Params p) {
  int w = (blockIdx.x * 256 + threadIdx.x) >> 6;
  int lane = threadIdx.x & 63;
  if (w >= p.N) return;
  int fl = lane & 15;
  float a[8] = {0.f, 0.f, 0.f, 0.f, 0.f, 0.f, 0.f, 0.f};
  gather_mean(p.Aq, p.Ascale, p.rowptr, p.srclist, w, lane, a);
  uint4 qv = ((const uint4*)p.Qbf)[(size_t)w * 16 + fl];
  float4 bl0 = *(const float4*)(p.b_l + fl * 8);
  float4 bl1 = *(const float4*)(p.b_l + fl * 8 + 4);
  float q[8] = {bflo(qv.x), bfhi(qv.x), bflo(qv.y), bfhi(qv.y), bflo(qv.z), bfhi(qv.z), bflo(qv.w), bfhi(qv.w)};
  float bl[8] = {bl0.x, bl0.y, bl0.z, bl0.w, bl1.x, bl1.y, bl1.z, bl1.w};
  float h[8];
#pragma unroll
  for (int k = 0; k < 8; ++k) h[k] = a[k] + q[k] + bl[k];
  float r[8];
  ln_relu8(h, p.gamma, p.beta, fl, r);
  if (lane < 16) {
    ((uint4*)p.H1)[(size_t)w * 16 + fl] = pack8(h);
    ((uint4*)p.Dbf)[(size_t)w * 16 + fl] = pack8(r);
  }
}

// agg2: o = relu(LN(mean(Aq)+Qbf+b_l+h1)) -> Dbf (bf16)
__global__ __launch_bounds__(256) void k_agg2(Params p) {
  int w = (blockIdx.x * 256 + threadIdx.x) >> 6;
  int lane = threadIdx.x & 63;
  if (w >= p.N) return;
  int fl = lane & 15;
  float a[8] = {0.f, 0.f, 0.f, 0.f, 0.f, 0.f, 0.f, 0.f};
  gather_mean(p.Aq, p.Ascale, p.rowptr, p.srclist, w, lane, a);
  uint4 vv = ((const uint4*)p.Qbf)[(size_t)w * 16 + fl];
  uint4 hv = ((const uint4*)p.H1)[(size_t)w * 16 + fl];
  float4 bl0 = *(const float4*)(p.b_l + fl * 8);
  float4 bl1 = *(const float4*)(p.b_l + fl * 8 + 4);
  float vf[8] = {bflo(vv.x), bfhi(vv.x), bflo(vv.y), bfhi(vv.y), bflo(vv.z), bfhi(vv.z), bflo(vv.w), bfhi(vv.w)};
  float hf[8] = {bflo(hv.x), bfhi(hv.x), bflo(hv.y), bfhi(hv.y), bflo(hv.z), bfhi(hv.z), bflo(hv.w), bfhi(hv.w)};
  float bl[8] = {bl0.x, bl0.y, bl0.z, bl0.w, bl1.x, bl1.y, bl1.z, bl1.w};
  float h[8];
#pragma unroll
  for (int k = 0; k < 8; ++k) h[k] = a[k] + vf[k] + bl[k] + hf[k];
  float o[8];
  ln_relu8(h, p.gamma, p.beta, fl, o);
  if (lane < 16) ((uint4*)p.Dbf)[(size_t)w * 16 + fl] = pack8(o);
}

// ================= launch =================

extern "C" void kernel_launch(void* const* d_in, const int* in_sizes, int n_in,
                              void* d_out, int out_size, void* d_ws, size_t ws_size,
                              hipStream_t stream) {
  Params p;
  p.x = (const float*)d_in[0];
  p.ei = (const int*)d_in[1];
  // d_in[2] = edge_attr: unused by the reference
  p.W_ne = (const float*)d_in[3];
  p.b_ne = (const float*)d_in[4];
  p.W_l = (const float*)d_in[5];
  p.b_l = (const float*)d_in[6];
  p.W_r = (const float*)d_in[7];
  p.gamma = (const float*)d_in[8];
  p.beta = (const float*)d_in[9];
  p.W_lin = (const float*)d_in[10];
  p.b_lin = (const float*)d_in[11];
  p.out = (float*)d_out;

  p.N = in_sizes[0] / 128;
  p.E = in_sizes[1] / 2;
  p.nbS = (p.N + 255) / 256;
  p.nbT = (p.N + 127) / 128;
  p.nbE = (p.E + 255) / 256;

  char* w = (char*)d_ws;
  const size_t S2 = (size_t)p.N * 128 * sizeof(ushort);
  p.Qbf = (ushort*)w;    w += S2;
  p.H1 = (ushort*)w;     w += S2;
  p.Dbf = (ushort*)w;    w += S2;
  p.xbf = (ushort*)w;    w += S2;
  p.Aq = (signed char*)w;  w += (size_t)p.N * 128;
  p.Ascale = (float*)w;  w += (size_t)p.N * sizeof(float);
  p.WAt = (ushort*)w;    w += 128 * 128 * sizeof(ushort);
  p.WBt = (ushort*)w;    w += 128 * 128 * sizeof(ushort);
  p.Wlt = (ushort*)w;    w += 128 * 128 * sizeof(ushort);
  p.Wrt = (ushort*)w;    w += 128 * 128 * sizeof(ushort);
  p.Wlint = (ushort*)w;  w += 64 * 128 * sizeof(ushort);
  p.bA = (float*)w;      w += 128 * sizeof(float);
  p.bB = (float*)w;      w += 128 * sizeof(float);
  p.cnt = (int*)w;       w += (size_t)p.N * sizeof(int);
  p.incl = (int*)w;      w += (size_t)p.N * sizeof(int);
  p.rowptr = (int*)w;    w += ((size_t)p.N + 4) * sizeof(int);
  p.cursor = (int*)w;    w += (size_t)p.N * sizeof(int);
  p.bsums = (int*)w;     w += 1024 * sizeof(int);
  p.srclist = (int*)w;

  const int nbW = ((p.N * 64) + 255) / 256;

  hipMemsetAsync(p.cnt, 0, (size_t)p.N * sizeof(int), stream);
  k_m1<<<p.nbE + 129 + 1024, 256, 0, stream>>>(p);
  k_m2<<<p.nbS + 2 * p.nbT, 256, 0, stream>>>(p);
  k_m3<<<p.nbS, 256, 0, stream>>>(p);
  k_fill<<<p.nbE, 256, 0, stream>>>(p);
  k_agg1<<<nbW, 256, 0, stream>>>(p);
  k_gemm2<<<dim3(p.nbT, 2), 256, 0, stream>>>(p);
  k_agg2<<<nbW, 256, 0, stream>>>(p);
  k_gout<<<p.nbT, 256, 0, stream>>>(p);
}